// Round 11
// baseline (285.350 us; speedup 1.0000x reference)
//
#include <hip/hip_runtime.h>
#include <cfloat>

#define NTOK (64 * 4096)   // 262144 tokens
#define HID  128
#define NE   64
#define TK   6
#define BLK  256
#define TPB  256           // tokens per block
#define GRID (NTOK / TPB)  // 1024 blocks
#define TST  33            // logit tile stride: odd -> <=2-way banks, no b128 merge

__global__ __launch_bounds__(BLK, 3)
void gate_kernel(const float* __restrict__ X,
                 const float* __restrict__ W,
                 float* __restrict__ oidx,
                 float* __restrict__ ow,
                 float* __restrict__ Pi_g,
                 unsigned int* __restrict__ cnt_g)
{
    // Phase GEMM  : smem[0..8192)  = W rotated: Wlds[k][(e + 4*((k>>2)&15)) & 63]
    // Phase EPI p : smem[0..8448)  = logits L[t][e_half] at t*33 + (e - 32p)
    __shared__ float        smem[TPB * TST];   // 33.8 KB (covers 32 KB W region)
    __shared__ float        mz[2 * TPB];
    __shared__ float        Pi_s[NE];
    __shared__ unsigned int cnt_s[NE];

    const int tid  = threadIdx.x;
    const int lane = tid & 63;
    const int wv   = __builtin_amdgcn_readfirstlane(tid >> 6);  // 0..3
    const int eb   = wv * 16;                  // this wave's 16 experts

    if (tid < NE) cnt_s[tid] = 0u;

    // ---- stage W rotated (one-time)
    {
        const float4* W4 = (const float4*)W;
#pragma unroll
        for (int i = 0; i < 8; ++i) {
            const int flat = tid + i * BLK;     // [0,2048) float4 index
            const float4 v = W4[flat];
            const int e   = flat >> 5;
            const int c   = flat & 31;          // k>>2
            const int col = (e + ((c & 15) << 2)) & 63;
            float* p = &smem[c * 256 + col];    // k rows 4c..4c+3
            p[0]   = v.x;
            p[64]  = v.y;
            p[128] = v.z;
            p[192] = v.w;
        }
    }
    __syncthreads();

    const int gtok0 = blockIdx.x * TPB;
    const float4* xr0 = (const float4*)(X + (size_t)(gtok0 + lane      ) * HID);
    const float4* xr1 = (const float4*)(X + (size_t)(gtok0 + lane +  64) * HID);
    const float4* xr2 = (const float4*)(X + (size_t)(gtok0 + lane + 128) * HID);
    const float4* xr3 = (const float4*)(X + (size_t)(gtok0 + lane + 192) * HID);

    float acc[4][16];
#pragma unroll
    for (int g = 0; g < 4; ++g)
#pragma unroll
        for (int j = 0; j < 16; ++j) acc[g][j] = 0.0f;

    // ---- GEMM, software-pipelined: X prefetched one c-iter ahead,
    //      W ds_reads double-buffered one d-group ahead.
    float4 nx0 = xr0[0], nx1 = xr1[0], nx2 = xr2[0], nx3 = xr3[0];

#pragma unroll 1
    for (int c = 0; c < 32; ++c) {             // k = 4c..4c+3
        float xs[4][4];
        xs[0][0]=nx0.x; xs[0][1]=nx0.y; xs[0][2]=nx0.z; xs[0][3]=nx0.w;
        xs[1][0]=nx1.x; xs[1][1]=nx1.y; xs[1][2]=nx1.z; xs[1][3]=nx1.w;
        xs[2][0]=nx2.x; xs[2][1]=nx2.y; xs[2][2]=nx2.z; xs[2][3]=nx2.w;
        xs[3][0]=nx3.x; xs[3][1]=nx3.y; xs[3][2]=nx3.z; xs[3][3]=nx3.w;

        const int cn = (c < 31) ? (c + 1) : 0;           // wave-uniform
        nx0 = xr0[cn]; nx1 = xr1[cn]; nx2 = xr2[cn]; nx3 = xr3[cn];

        const int rr = (c & 15) << 2;
        const float* rowb = &smem[c * 256];
        const float* p0 = &rowb[(eb +  0 + rr) & 63];
        const float* p1 = &rowb[(eb +  4 + rr) & 63];
        const float* p2 = &rowb[(eb +  8 + rr) & 63];
        const float* p3 = &rowb[(eb + 12 + rr) & 63];

        float4 wA0 = *(const float4*)(p0);
        float4 wA1 = *(const float4*)(p1);
        float4 wA2 = *(const float4*)(p2);
        float4 wA3 = *(const float4*)(p3);

#pragma unroll
        for (int d = 0; d < 4; ++d) {
            float4 wB0, wB1, wB2, wB3;
            if (d < 3) {
                wB0 = *(const float4*)(p0 + 64*(d+1));
                wB1 = *(const float4*)(p1 + 64*(d+1));
                wB2 = *(const float4*)(p2 + 64*(d+1));
                wB3 = *(const float4*)(p3 + 64*(d+1));
            }
#pragma unroll
            for (int g = 0; g < 4; ++g) {
                const float xv = xs[g][d];
                acc[g][ 0] = fmaf(xv, wA0.x, acc[g][ 0]);
                acc[g][ 1] = fmaf(xv, wA0.y, acc[g][ 1]);
                acc[g][ 2] = fmaf(xv, wA0.z, acc[g][ 2]);
                acc[g][ 3] = fmaf(xv, wA0.w, acc[g][ 3]);
                acc[g][ 4] = fmaf(xv, wA1.x, acc[g][ 4]);
                acc[g][ 5] = fmaf(xv, wA1.y, acc[g][ 5]);
                acc[g][ 6] = fmaf(xv, wA1.z, acc[g][ 6]);
                acc[g][ 7] = fmaf(xv, wA1.w, acc[g][ 7]);
                acc[g][ 8] = fmaf(xv, wA2.x, acc[g][ 8]);
                acc[g][ 9] = fmaf(xv, wA2.y, acc[g][ 9]);
                acc[g][10] = fmaf(xv, wA2.z, acc[g][10]);
                acc[g][11] = fmaf(xv, wA2.w, acc[g][11]);
                acc[g][12] = fmaf(xv, wA3.x, acc[g][12]);
                acc[g][13] = fmaf(xv, wA3.y, acc[g][13]);
                acc[g][14] = fmaf(xv, wA3.z, acc[g][14]);
                acc[g][15] = fmaf(xv, wA3.w, acc[g][15]);
            }
            if (d < 3) { wA0 = wB0; wA1 = wB1; wA2 = wB2; wA3 = wB3; }
        }
    }

    __syncthreads();   // all waves done reading W -> tile region reusable

    // ---- expert-split epilogue: two passes, ALL 256 threads busy in both.
    //      Carried top-6 state over ascending e == single-pass scan (jax ties).
    float tv[TK]; int ti[TK];
#pragma unroll
    for (int q = 0; q < TK; ++q) { tv[q] = -FLT_MAX; ti[q] = 0; }
    float m0, s0, m1, s1;

    // ======== pass 0: experts 0..31 (waves 0,1 scatter) ========
    if (wv < 2) {
#pragma unroll
        for (int g = 0; g < 4; ++g) {
            float* p = &smem[(lane + 64*g) * TST + eb];
#pragma unroll
            for (int j = 0; j < 16; ++j) p[j] = acc[g][j];
        }
    }
    __syncthreads();
    {
        const float* Lrow = &smem[tid * TST];
#pragma unroll 8
        for (int e = 0; e < 32; ++e) {
            float m = Lrow[e];
            int   mi = e;
#pragma unroll
            for (int q = 0; q < TK; ++q) {
                const bool  cx = m > tv[q];       // strict >: stable tie order
                const float nt = cx ? m     : tv[q];
                const float nm = cx ? tv[q] : m;
                const int   ni = cx ? mi    : ti[q];
                const int   nj = cx ? ti[q] : mi;
                tv[q] = nt; m = nm; ti[q] = ni; mi = nj;
            }
        }
        m0 = tv[0];                               // max over experts 0..31
        float ss = 0.0f;
#pragma unroll 8
        for (int e = 0; e < 32; ++e) ss += __expf(Lrow[e] - m0);
        s0 = ss;
    }
    __syncthreads();   // pass-0 reads done before pass-1 scatter

    // ======== pass 1: experts 32..63 (waves 2,3 scatter) ========
    if (wv >= 2) {
#pragma unroll
        for (int g = 0; g < 4; ++g) {
            float* p = &smem[(lane + 64*g) * TST + (eb - 32)];
#pragma unroll
            for (int j = 0; j < 16; ++j) p[j] = acc[g][j];
        }
    }
    __syncthreads();
    {
        const float* Lrow = &smem[tid * TST];
        float pm = -FLT_MAX;
#pragma unroll 8
        for (int e2 = 0; e2 < 32; ++e2) {
            float m = Lrow[e2];
            pm = fmaxf(pm, m);
            int mi = 32 + e2;
#pragma unroll
            for (int q = 0; q < TK; ++q) {
                const bool  cx = m > tv[q];
                const float nt = cx ? m     : tv[q];
                const float nm = cx ? tv[q] : m;
                const int   ni = cx ? mi    : ti[q];
                const int   nj = cx ? ti[q] : mi;
                tv[q] = nt; m = nm; ti[q] = ni; mi = nj;
            }
        }
        m1 = pm;                                  // max over experts 32..63
        float ss = 0.0f;
#pragma unroll 8
        for (int e2 = 0; e2 < 32; ++e2) ss += __expf(Lrow[e2] - m1);
        s1 = ss;
    }

    // ---- finalize outputs for this thread's token
    {
        const float mx = tv[0];
        const float Z  = s0 * __expf(m0 - mx) + s1 * __expf(m1 - mx);
        const float rz = 1.0f / Z;

        float ex[TK]; float s = 0.0f;
#pragma unroll
        for (int q = 0; q < TK; ++q) { ex[q] = __expf(tv[q] - mx); s += ex[q]; }
        const float rs = 1.0f / (s + 1e-20f);

        const size_t gt = (size_t)(gtok0 + tid) * TK;
        float2* ip = (float2*)(oidx + gt);
        float2* wp = (float2*)(ow + gt);
        ip[0] = make_float2((float)ti[0], (float)ti[1]);
        ip[1] = make_float2((float)ti[2], (float)ti[3]);
        ip[2] = make_float2((float)ti[4], (float)ti[5]);
        wp[0] = make_float2(ex[0]*rs, ex[1]*rs);
        wp[1] = make_float2(ex[2]*rs, ex[3]*rs);
        wp[2] = make_float2(ex[4]*rs, ex[5]*rs);

#pragma unroll
        for (int q = 0; q < TK; ++q) atomicAdd(&cnt_s[ti[q]], 1u);

        mz[2*tid]     = mx;
        mz[2*tid + 1] = rz;
    }
    __syncthreads();   // mz ready; pass-1 tile reads complete

    // ---- Pi from acc (raw logits, compile-time indices) + mz
    {
        float pi[16];
#pragma unroll
        for (int j = 0; j < 16; ++j) pi[j] = 0.0f;
#pragma unroll
        for (int g = 0; g < 4; ++g) {
            const int t = lane + 64 * g;
            const float mxt = mz[2*t];
            const float rzt = mz[2*t + 1];
#pragma unroll
            for (int j = 0; j < 16; ++j)
                pi[j] += __expf(acc[g][j] - mxt) * rzt;
        }
#pragma unroll
        for (int s = 1; s <= 32; s <<= 1) {
#pragma unroll
            for (int j = 0; j < 16; ++j) pi[j] += __shfl_xor(pi[j], s);
        }
        if (lane < 16) Pi_s[eb + lane] = pi[lane];   // waves own disjoint experts
    }
    __syncthreads();

    if (tid < NE) {
        atomicAdd(&Pi_g[tid], Pi_s[tid]);
        atomicAdd(&cnt_g[tid], cnt_s[tid]);
    }
}

__global__ void aux_kernel(const float* __restrict__ Pi_g,
                           const unsigned int* __restrict__ cnt_g,
                           float* __restrict__ out_aux)
{
    const int e = threadIdx.x;   // 64 threads
    const float Pi = Pi_g[e] * (1.0f / (float)NTOK);
    const float ce = (float)cnt_g[e] * (1.0f / (float)(NTOK * TK));
    float v = Pi * ce * (float)NE;
#pragma unroll
    for (int off = 32; off > 0; off >>= 1) v += __shfl_down(v, off);
    if (e == 0) out_aux[0] = v * 1.0e-3f;
}

extern "C" void kernel_launch(void* const* d_in, const int* in_sizes, int n_in,
                              void* d_out, int out_size, void* d_ws, size_t ws_size,
                              hipStream_t stream) {
    const float* X = (const float*)d_in[0];
    const float* W = (const float*)d_in[1];

    float* out  = (float*)d_out;
    float* oidx = out;                          // N*6 indices (as float)
    float* ow   = out + (size_t)NTOK * TK;      // N*6 weights
    float* aux  = out + (size_t)NTOK * TK * 2;  // 1 scalar

    float*        Pi_g  = (float*)d_ws;
    unsigned int* cnt_g = (unsigned int*)((char*)d_ws + 256);

    hipMemsetAsync(d_ws, 0, 512, stream);
    gate_kernel<<<GRID, BLK, 0, stream>>>(X, W, oidx, ow, Pi_g, cnt_g);
    aux_kernel<<<1, 64, 0, stream>>>(Pi_g, cnt_g, aux);
}